// Round 8
// baseline (389.660 us; speedup 1.0000x reference)
//
#include <hip/hip_runtime.h>
#include <math.h>

#define B_ 16
#define H_ 16
#define M_ 256
#define N_ 576
#define D_ 1024
#define BK 64
#define LDS_STRIDE (BK + 8)
#define NROWS (B_ * N_ + B_ * M_)   // 13312 feature rows to normalize

constexpr float EPS_ = 1e-8f;
constexpr float FI_ = 0.90909090909090906f;   // RHO/(RHO+EPSILON) = 1/1.1

typedef __bf16 bf16x8 __attribute__((ext_vector_type(8)));
typedef float f32x4 __attribute__((ext_vector_type(4)));

__device__ __forceinline__ float wave_reduce(float v) {
#pragma unroll
  for (int o = 32; o > 0; o >>= 1) v += __shfl_down(v, o, 64);
  return v;
}

__device__ __forceinline__ unsigned short f2bf(float f) {
  union { float f; unsigned u; } a; a.f = f;
  unsigned r = a.u + 0x7fff + ((a.u >> 16) & 1);   // RNE
  return (unsigned short)(r >> 16);
}

__device__ __forceinline__ float bf2f(unsigned short u) {
  union { unsigned u; float f; } a; a.u = ((unsigned)u) << 16;
  return a.f;
}

// packed-pair bf16 -> f32 (bit-exact with bf2f)
__device__ __forceinline__ float bflo(unsigned p) {
  union { unsigned u; float f; } a; a.u = p << 16; return a.f;
}
__device__ __forceinline__ float bfhi(unsigned p) {
  union { unsigned u; float f; } a; a.u = p & 0xffff0000u; return a.f;
}

// L2-normalize+bf16-cast vis (B*N rows) and txt (B*M rows), one wave per row;
// trailing 4 blocks: masksum[b] and vv := 1.0 (first sink iteration input).
__global__ __launch_bounds__(256) void prep_kernel(const float* __restrict__ vis,
                                                   const float* __restrict__ txt,
                                                   const float* __restrict__ mask,
                                                   unsigned short* __restrict__ xb,
                                                   unsigned short* __restrict__ yb,
                                                   float* __restrict__ masksum,
                                                   float* __restrict__ vv) {
  const int bid = blockIdx.x;
  const int lane = threadIdx.x & 63;
  if (bid < NROWS / 4) {
    int wave = bid * 4 + (threadIdx.x >> 6);
    const float* src;
    unsigned short* dst;
    if (wave < B_ * N_) {
      src = vis + (size_t)wave * D_;
      dst = xb + (size_t)wave * D_;
    } else {
      int r = wave - B_ * N_;
      src = txt + (size_t)r * D_;
      dst = yb + (size_t)r * D_;
    }
    float4 v[4];
    float s = 0.f;
#pragma unroll
    for (int it = 0; it < 4; ++it) {
      v[it] = *(const float4*)&src[it * 256 + lane * 4];
      s += v[it].x * v[it].x + v[it].y * v[it].y + v[it].z * v[it].z + v[it].w * v[it].w;
    }
    s = wave_reduce(s);
    s = __shfl(s, 0, 64);
    float inv = rsqrtf(s + 1e-12f);
#pragma unroll
    for (int it = 0; it < 4; ++it) {
      ushort4 pk;
      pk.x = f2bf(v[it].x * inv);
      pk.y = f2bf(v[it].y * inv);
      pk.z = f2bf(v[it].z * inv);
      pk.w = f2bf(v[it].w * inv);
      *(ushort4*)&dst[it * 256 + lane * 4] = pk;
    }
  } else {
    const int g = bid - NROWS / 4;                       // 0..3
    for (int i = threadIdx.x; i < 4 * N_; i += 256) vv[g * 4 * N_ + i] = 1.f;
    int b = g * 4 + (threadIdx.x >> 6);                  // 0..15
    float4 mv = *(const float4*)&mask[b * M_ + lane * 4];
    float s = wave_reduce(mv.x + mv.y + mv.z + mv.w);
    if (lane == 0) masksum[b] = s;
  }
}

// K[b,m,n] = bf16(exp(10*(dot(yb[b,m],xb[b,n]) - 1))), bf16 MFMA 16x16x32,
// 64x64 tile/block, 4 waves each computing a 32x32 sub-tile (2x2 frags).
__global__ __launch_bounds__(256) void gemm_k_mfma(const unsigned short* __restrict__ xb,
                                                   const unsigned short* __restrict__ yb,
                                                   unsigned short* __restrict__ Kw) {
  __shared__ unsigned short As[64][LDS_STRIDE];  // y rows (m)
  __shared__ unsigned short Bs[64][LDS_STRIDE];  // x rows (n)
  const int b = blockIdx.z;
  const int m0 = blockIdx.y * 64;
  const int n0 = blockIdx.x * 64;
  const unsigned short* Y = yb + (size_t)b * M_ * D_;
  const unsigned short* X = xb + (size_t)b * N_ * D_;
  const int t = threadIdx.x;
  const int lane = t & 63;
  const int w = t >> 6;
  const int wm = (w & 1) * 32;
  const int wn = (w >> 1) * 32;
  const int lr = t >> 3;           // 0..31 staging row
  const int lc = (t & 7) * 8;      // staging col (bf16 units, 16B chunks)
  const int fr = lane & 15;        // fragment row within 16
  const int fk = (lane >> 4) * 8;  // fragment k offset

  f32x4 acc[2][2] = {};
  for (int k0 = 0; k0 < D_; k0 += BK) {
#pragma unroll
    for (int p = 0; p < 2; ++p) {
      *(uint4*)&As[lr + 32 * p][lc] = *(const uint4*)&Y[(size_t)(m0 + lr + 32 * p) * D_ + k0 + lc];
      *(uint4*)&Bs[lr + 32 * p][lc] = *(const uint4*)&X[(size_t)(n0 + lr + 32 * p) * D_ + k0 + lc];
    }
    __syncthreads();
#pragma unroll
    for (int ks = 0; ks < BK; ks += 32) {
      bf16x8 a[2], bfr[2];
#pragma unroll
      for (int i = 0; i < 2; ++i) {
        a[i] = *(const bf16x8*)&As[wm + i * 16 + fr][ks + fk];
        bfr[i] = *(const bf16x8*)&Bs[wn + i * 16 + fr][ks + fk];
      }
#pragma unroll
      for (int i = 0; i < 2; ++i)
#pragma unroll
        for (int j = 0; j < 2; ++j)
          acc[i][j] = __builtin_amdgcn_mfma_f32_16x16x32_bf16(a[i], bfr[j], acc[i][j], 0, 0, 0);
    }
    __syncthreads();
  }

  // C/D layout: m = (lane>>4)*4 + reg, n = lane&15
  const int cm = (lane >> 4) * 4;
  const int cn = lane & 15;
#pragma unroll
  for (int i = 0; i < 2; ++i)
#pragma unroll
    for (int j = 0; j < 2; ++j)
#pragma unroll
      for (int rg = 0; rg < 4; ++rg) {
        int m = m0 + wm + i * 16 + cm + rg;
        int n = n0 + wn + j * 16 + cn;
        Kw[((size_t)b * M_ + m) * N_ + n] = f2bf(expf(10.f * (acc[i][j][rg] - 1.f)));
      }
}

// One full Sinkhorn iteration per launch (u-step + v-step), NO cross-block
// sync, bit-exact vs the verified split kernels:
//   Phase A (u, redundant across the 9 blocks of a batch): thread t owns row t.
//     It builds the 64 lane-partials p[l] = sum_k K[t, l+64k]*v[l+64k]
//     (k ascending -- identical per-partial order), then emulates the
//     shfl_down butterfly IN-REGISTER: for off in {32,16,8,4,2,1}:
//     p[l] += p[l+off] (l<off). This is the exact same addition tree as
//     wave_reduce, so s (= p[0]) is bit-identical. u = powf(nu/(s+EPS), FI).
//   Phase B: verbatim round-0 sink_v body (wave w sums rows w*64..w*64+63
//     sequentially for its 64 columns; quarters combined in exact order),
//     u read from LDS (bit-identical values).
// First iteration consumes v==1.0 from prep (x*1.0f is bit-exact).
__global__ __launch_bounds__(256) void sink_uv_kernel(
    const unsigned short* __restrict__ Kw, const float* __restrict__ mask,
    const float* __restrict__ msum, float* __restrict__ vv) {
  __shared__ float v_s[N_];
  __shared__ float u_s[M_];
  __shared__ float part[4][64];
  const int b = blockIdx.x / 9;
  const int vblk = blockIdx.x - b * 9;
  const int t = threadIdx.x;
  const int lane = t & 63;
  const int w = t >> 6;
  const unsigned short* Kb = Kw + (size_t)b * M_ * N_;

  for (int n = t; n < N_; n += 256) v_s[n] = vv[b * N_ + n];
  __syncthreads();

  // ---- Phase A: row t, 64 in-register lane-partials + exact butterfly ----
  float p[64];
#pragma unroll
  for (int l = 0; l < 64; ++l) p[l] = 0.f;
  const unsigned short* rowp = Kb + (size_t)t * N_;
#pragma unroll
  for (int k = 0; k < 9; ++k) {
    uint4 c[8];
#pragma unroll
    for (int j = 0; j < 8; ++j) c[j] = *(const uint4*)&rowp[k * 64 + j * 8];
#pragma unroll
    for (int l = 0; l < 64; ++l) {
      const unsigned word = ((const unsigned*)c)[l >> 1];   // static after unroll
      const float kv = (l & 1) ? bfhi(word) : bflo(word);
      p[l] += kv * v_s[k * 64 + l];                          // broadcast LDS read
    }
  }
#pragma unroll
  for (int off = 32; off > 0; off >>= 1)
#pragma unroll
    for (int l = 0; l < 32; ++l)
      if (l < off) p[l] += p[l + off];
  const float s = p[0];
  const float nu = mask[b * M_ + t] / (msum[b] + EPS_);
  u_s[t] = powf(nu / (s + EPS_), FI_);
  __syncthreads();

  // ---- Phase B: exact round-0 sink_v body for cols vblk*64..+63 ----
  const int col = vblk * 64 + lane;
  float sv = 0.f;
#pragma unroll 8
  for (int m = w * 64; m < (w + 1) * 64; ++m)
    sv += bf2f(Kb[(size_t)m * N_ + col]) * u_s[m];
  part[w][lane] = sv;
  __syncthreads();
  if (t < 64) {
    float tot = part[0][t] + part[1][t] + part[2][t] + part[3][t];
    vv[b * N_ + vblk * 64 + t] = powf((1.f / (float)N_) / (tot + EPS_), FI_);
  }
}

// Per (b,m) row, SL computed INLINE (single HBM pass over student; no SL
// buffer): sl[n] = sum_h log(student[b,h,m,n]+EPS) ascending-h (bit-identical
// to the old sumlog), then s1 = sum_n K*v, s2 = sum_n K*v*sl, exact round-0
// reduction pattern. partial[row] = -mask*s2/((s1+EPS)*B*H*M).
__global__ __launch_bounds__(256) void finloss_kernel(
    const unsigned short* __restrict__ Kw, const float* __restrict__ student,
    const float* __restrict__ v, const float* __restrict__ mask,
    float* __restrict__ partial) {
  __shared__ float red[2][4];
  const int m = blockIdx.x;
  const int b = blockIdx.y;
  const int t = threadIdx.x;
  float s1 = 0.f, s2 = 0.f;
  if (t < N_ / 4) {
    const float* st = student + (size_t)b * H_ * M_ * N_ + (size_t)m * N_ + t * 4;
    float4 sl = {0.f, 0.f, 0.f, 0.f};
#pragma unroll
    for (int h = 0; h < H_; ++h) {
      float4 s4 = *(const float4*)&st[(size_t)h * M_ * N_];
      sl.x += __logf(s4.x + EPS_);
      sl.y += __logf(s4.y + EPS_);
      sl.z += __logf(s4.z + EPS_);
      sl.w += __logf(s4.w + EPS_);
    }
    ushort4 k4 = *(const ushort4*)&Kw[((size_t)b * M_ + m) * N_ + t * 4];
    float4 v4 = *(const float4*)&v[b * N_ + t * 4];
    float kv0 = bf2f(k4.x) * v4.x, kv1 = bf2f(k4.y) * v4.y;
    float kv2 = bf2f(k4.z) * v4.z, kv3 = bf2f(k4.w) * v4.w;
    s1 = kv0 + kv1 + kv2 + kv3;
    s2 = kv0 * sl.x + kv1 * sl.y + kv2 * sl.z + kv3 * sl.w;
  }
  s1 = wave_reduce(s1);
  s2 = wave_reduce(s2);
  if ((t & 63) == 0) { red[0][t >> 6] = s1; red[1][t >> 6] = s2; }
  __syncthreads();
  if (t == 0) {
    float S1 = red[0][0] + red[0][1] + red[0][2] + red[0][3];
    float S2 = red[1][0] + red[1][1] + red[1][2] + red[1][3];
    int row = b * M_ + m;
    partial[row] = -mask[row] * S2 / ((S1 + EPS_) * (float)(B_ * H_ * M_));
  }
}

// Sum 4096 partials -> d_out[0]. Single block.
__global__ __launch_bounds__(256) void reduce_kernel(const float* __restrict__ partial,
                                                     float* __restrict__ out) {
  __shared__ float red[4];
  float s = 0.f;
  for (int i = threadIdx.x; i < B_ * M_; i += 256) s += partial[i];
  s = wave_reduce(s);
  if ((threadIdx.x & 63) == 0) red[threadIdx.x >> 6] = s;
  __syncthreads();
  if (threadIdx.x == 0) out[0] = red[0] + red[1] + red[2] + red[3];
}

extern "C" void kernel_launch(void* const* d_in, const int* in_sizes, int n_in,
                              void* d_out, int out_size, void* d_ws, size_t ws_size,
                              hipStream_t stream) {
  const float* student = (const float*)d_in[0];  // (B,H,M,N)
  const float* vis = (const float*)d_in[1];      // (B,N,D)
  const float* txt = (const float*)d_in[2];      // (B,M,D)
  const float* mask = (const float*)d_in[3];     // (B,M)
  float* out = (float*)d_out;

  char* p = (char*)d_ws;
  unsigned short* Kw = (unsigned short*)p; p += (size_t)B_ * M_ * N_ * 2;   // 4.7 MB
  unsigned short* xb = (unsigned short*)p; p += (size_t)B_ * N_ * D_ * 2;   // 18.9 MB
  unsigned short* yb = (unsigned short*)p; p += (size_t)B_ * M_ * D_ * 2;   // 8.4 MB
  float* msum = (float*)p;    p += 256;
  float* vv = (float*)p;      p += (size_t)B_ * N_ * 4;
  float* partial = (float*)p; p += (size_t)B_ * M_ * 4;

  prep_kernel<<<NROWS / 4 + 4, 256, 0, stream>>>(vis, txt, mask, xb, yb, msum, vv);
  gemm_k_mfma<<<dim3(N_ / 64, M_ / 64, B_), 256, 0, stream>>>(xb, yb, Kw);
  for (int it = 0; it < 5; ++it)
    sink_uv_kernel<<<B_ * 9, 256, 0, stream>>>(Kw, mask, msum, vv);
  finloss_kernel<<<dim3(M_, B_), 256, 0, stream>>>(Kw, student, vv, mask, partial);
  reduce_kernel<<<1, 256, 0, stream>>>(partial, out);
}